// Round 16
// baseline (140.028 us; speedup 1.0000x reference)
//
#include <hip/hip_runtime.h>

#define N_NODES  100000
#define N_EDGES  1250000
#define N_GRAPHS 1024
#define NB       ((N_NODES + 127) >> 7)     // 782 coarse buckets of 128 nodes
#define NB2      (N_NODES / 16)             // 6250 conv tiles of 16 nodes (exact)
#define NBLK_F   500                         // fill blocks
#define EPB      (N_EDGES / NBLK_F)          // 2500 edges per fill block (exact)
#define EMB_BLKS ((N_NODES + 255) / 256)     // 391
#define CAP      512                         // per-tile edge capacity (mean 200)

typedef __attribute__((ext_vector_type(8))) short short8;
typedef __attribute__((ext_vector_type(4))) float f32x4;
union U16 { uint4 u; short8 s; };

// ---- bf16 helpers (round-to-nearest-even) ----
__device__ __forceinline__ float bflo(unsigned int w) { return __uint_as_float(w << 16); }
__device__ __forceinline__ float bfhi(unsigned int w) { return __uint_as_float(w & 0xffff0000u); }
__device__ __forceinline__ unsigned short f2bf(float f) {
  unsigned int u = __float_as_uint(f);
  u = (u + 0x7fffu + ((u >> 16) & 1u)) >> 16;
  return (unsigned short)u;
}
__device__ __forceinline__ unsigned int pack2(float a, float b) {
  return (unsigned int)f2bf(a) | ((unsigned int)f2bf(b) << 16);
}

// ------- pack Wcat = [wrel; wroot] (2*DIN x 64) into MFMA B-fragments -------
template <int DIN>
__device__ __forceinline__ void prep_body(int t, const float* __restrict__ wrel,
                                          const float* __restrict__ wroot,
                                          unsigned short* __restrict__ Bf) {
  constexpr int NKC = (2 * DIN) / 32;
  if (t >= NKC * 4 * 64) return;
  int l = t & 63;
  int ct = (t >> 6) & 3;
  int kc = t >> 8;
  int col = ct * 16 + (l & 15);
#pragma unroll
  for (int e = 0; e < 8; ++e) {
    int k = kc * 32 + ((l >> 4) << 3) + e;
    float v = (k < DIN) ? wrel[col * DIN + k] : wroot[col * DIN + (k - DIN)];
    Bf[(size_t)t * 8 + e] = f2bf(v);
  }
}

// ------- fused front: embed+lin | weight prep | per-block coarse histogram -------
__global__ void __launch_bounds__(256)
k_front(const int* __restrict__ tok,
        const float* __restrict__ semb, const float* __restrict__ cemb,
        const float* __restrict__ lw, const float* __restrict__ lb,
        unsigned short* __restrict__ x1,          // [N,32] bf16
        const float* __restrict__ w1rel, const float* __restrict__ w1root,
        const float* __restrict__ w2rel, const float* __restrict__ w2root,
        unsigned short* __restrict__ Bf1, unsigned short* __restrict__ Bf2,
        const int* __restrict__ dst, int* __restrict__ hist) {
  __shared__ int lh[NB];
  const int t = threadIdx.x;
  const int bid = blockIdx.x;
  if (bid < EMB_BLKS) {
    int i = bid * 256 + t;
    if (i >= N_NODES) return;
    int s = tok[2 * i], c = tok[2 * i + 1];
    float e[16];
#pragma unroll
    for (int k = 0; k < 8; ++k) { e[k] = semb[s * 8 + k]; e[8 + k] = cemb[c * 8 + k]; }
    unsigned int w[16];
#pragma unroll
    for (int o = 0; o < 16; ++o) {
      float a0 = lb[2 * o], a1 = lb[2 * o + 1];
#pragma unroll
      for (int k = 0; k < 16; ++k) {
        a0 = fmaf(e[k], lw[(2 * o) * 16 + k], a0);
        a1 = fmaf(e[k], lw[(2 * o + 1) * 16 + k], a1);
      }
      w[o] = pack2(fmaxf(a0, 0.f), fmaxf(a1, 0.f));
    }
    uint4* d4 = (uint4*)(x1 + (size_t)i * 32);
#pragma unroll
    for (int q = 0; q < 4; ++q)
      d4[q] = make_uint4(w[4 * q], w[4 * q + 1], w[4 * q + 2], w[4 * q + 3]);
  } else if (bid < EMB_BLKS + 6) {
    int pb = bid - EMB_BLKS;
    if (pb < 2) prep_body<32>(pb * 256 + t, w1rel, w1root, Bf1);
    else prep_body<64>((pb - 2) * 256 + t, w2rel, w2root, Bf2);
  } else {
    const int blk = bid - EMB_BLKS - 6;           // 0..NBLK_F-1
    for (int i = t; i < NB; i += 256) lh[i] = 0;
    __syncthreads();
    const int start = blk * EPB;
    for (int e = start + t; e < start + EPB; e += 256)
      atomicAdd(&lh[dst[e] >> 7], 1);
    __syncthreads();
    int* hrow = hist + (size_t)blk * NB;          // [blk][bucket]: coalesced dump
    for (int i = t; i < NB; i += 256)
      hrow[i] = lh[i];
  }
}

// ------- per-bucket exclusive scan across fill blocks + bucket totals -------
__global__ void __launch_bounds__(512)
k_colscan(int* __restrict__ hist, int* __restrict__ btotal) {
  __shared__ int sc[512];
  const int b = blockIdx.x;
  const int t = threadIdx.x;
  int v = (t < NBLK_F) ? hist[(size_t)t * NB + b] : 0;
  sc[t] = v;
  __syncthreads();
  for (int off = 1; off < 512; off <<= 1) {
    int x = (t >= off) ? sc[t - off] : 0;
    __syncthreads();
    sc[t] += x;
    __syncthreads();
  }
  if (t < NBLK_F) hist[(size_t)t * NB + b] = sc[t] - v;
  if (t == 511) btotal[b] = sc[511];
}

// ------- fill: cursors = in-block scan(btotal) + per-block offset -------
__global__ void __launch_bounds__(256)
k_bfill(const int* __restrict__ src, const int* __restrict__ dst,
        const int* __restrict__ btotal, const int* __restrict__ hist,
        int* __restrict__ tmp) {
  __shared__ int cur[NB];
  __shared__ int spart[256];
  const int t = threadIdx.x;
  const int blk = blockIdx.x;
  const int* hrow = hist + (size_t)blk * NB;
  int v[4]; int s = 0;
#pragma unroll
  for (int j = 0; j < 4; ++j) {
    int idx = t * 4 + j;
    v[j] = (idx < NB) ? btotal[idx] : 0;
    s += v[j];
  }
  spart[t] = s;
  __syncthreads();
  for (int off = 1; off < 256; off <<= 1) {
    int x = (t >= off) ? spart[t - off] : 0;
    __syncthreads();
    spart[t] += x;
    __syncthreads();
  }
  int run = spart[t] - s;
#pragma unroll
  for (int j = 0; j < 4; ++j) {
    int idx = t * 4 + j;
    if (idx < NB) cur[idx] = run + hrow[idx];
    run += v[j];
  }
  __syncthreads();
  const int start = blk * EPB;
  for (int e = start + t; e < start + EPB; e += 256) {
    int d = dst[e];
    int pos = atomicAdd(&cur[d >> 7], 1);         // LDS only; block-owned range
    tmp[pos] = (src[e] << 7) | (d & 127);
  }
}

// ------- per-128-bucket finalize: full node sort -> esrc, deg, rowst -------
__global__ void __launch_bounds__(256)
k_bfinal(const int* __restrict__ btotal, const int* __restrict__ tmp,
         int* __restrict__ deg, int* __restrict__ rowst,
         int* __restrict__ esrc) {
  __shared__ int spart[256];
  __shared__ int h[128], sc[128], cur[128];
  __shared__ int s_base;
  const int t = threadIdx.x;
  const int b = blockIdx.x;
  int s = 0;
  for (int i = t; i < b; i += 256) s += btotal[i];
  spart[t] = s;
  if (t < 128) h[t] = 0;
  __syncthreads();
  for (int off = 128; off >= 1; off >>= 1) {
    if (t < off) spart[t] += spart[t + off];
    __syncthreads();
  }
  if (t == 0) s_base = spart[0];
  __syncthreads();
  const int base = s_base, cnt = btotal[b];
  for (int i = t; i < cnt; i += 256) atomicAdd(&h[tmp[base + i] & 127], 1);
  __syncthreads();
  if (t < 128) sc[t] = h[t];
  __syncthreads();
  for (int off = 1; off < 128; off <<= 1) {
    int v = 0;
    if (t < 128 && t >= off) v = sc[t - off];
    __syncthreads();
    if (t < 128) sc[t] += v;
    __syncthreads();
  }
  if (t < 128) {
    int excl = sc[t] - h[t];
    cur[t] = excl;
    int node = (b << 7) + t;
    if (node < N_NODES) { deg[node] = h[t]; rowst[node] = base + excl; }
  }
  __syncthreads();
  for (int i = t; i < cnt; i += 256) {
    int v = tmp[base + i];
    int p = atomicAdd(&cur[v & 127], 1);
    esrc[base + p] = v >> 7;
  }
}

// ======= per-tile conv: stage pre-sorted segment, uint2 reg-gather, MFMA =======
// FUSE_POOL=false: Y = relu(...) as bf16 [N,64].
// FUSE_POOL=true:  relu(...) summed per graph into f32 sums[G,64] (batch sorted).
template <int DIN, bool FUSE_POOL>
__global__ void __launch_bounds__(256)
k_conv(const int* __restrict__ deg, const int* __restrict__ rowst,
       const int* __restrict__ esrc,
       const unsigned short* __restrict__ X,    // [N,DIN] bf16
       const uint4* __restrict__ Bf,            // MFMA B-fragments, K=2*DIN
       const float* __restrict__ bias,          // [64]
       const int* __restrict__ batch,
       void* __restrict__ outv) {
  constexpr int NKC = (2 * DIN) / 32;      // 2 (conv1) / 4 (conv2)
  constexpr int LPGu = DIN / 4;            // lanes per edge (uint2 slice): 8 / 16
  constexpr int GROUPS = 64 / LPGu;        // 8 / 4
  __shared__ int lsrc[CAP];
  __shared__ int hdeg[16], hbase[16];
  __shared__ int s_cnt, s_base;
  __shared__ unsigned short aggT[(DIN / 8) * 16 * 8];   // [chunk][row][8] bf16
  const int t = threadIdx.x;
  const int lane = t & 63;
  const int wv = t >> 6;
  const int b = blockIdx.x;                // 16-node tile
  if (t < 16) hdeg[t] = deg[b * 16 + t];
  __syncthreads();
  if (t == 0) {
    int run = 0;
#pragma unroll
    for (int n = 0; n < 16; ++n) { hbase[n] = run; run += hdeg[n]; }
    s_cnt = min(run, CAP);
    s_base = rowst[b * 16];
  }
  __syncthreads();
  const int cnt = s_cnt, base = s_base;
  for (int i = t; i < cnt; i += 256) lsrc[i] = esrc[base + i];   // pre-sorted
  __syncthreads();

  // ---- gather: wave wv accumulates its 4 nodes in registers ----
  const int sub = lane / LPGu;
  const int lg = lane % LPGu;
#pragma unroll
  for (int k = 0; k < 4; ++k) {
    const int n = wv * 4 + k;
    const int dgn = hdeg[n];
    const int eb = hbase[n];
    float a0 = 0.f, a1 = 0.f, a2 = 0.f, a3 = 0.f;
    for (int j = 0; j < dgn; j += 2 * GROUPS) {
      int e0 = j + sub, e1 = j + GROUPS + sub;
      int s0 = lsrc[min(eb + min(e0, dgn - 1), CAP - 1)];
      int s1 = lsrc[min(eb + min(e1, dgn - 1), CAP - 1)];
      uint2 r0 = *((const uint2*)(X + (size_t)s0 * DIN) + lg);
      uint2 r1 = *((const uint2*)(X + (size_t)s1 * DIN) + lg);
      if (e0 < dgn) { a0 += bflo(r0.x); a1 += bfhi(r0.x); a2 += bflo(r0.y); a3 += bfhi(r0.y); }
      if (e1 < dgn) { a0 += bflo(r1.x); a1 += bfhi(r1.x); a2 += bflo(r1.y); a3 += bfhi(r1.y); }
    }
#pragma unroll
    for (int off = LPGu; off < 64; off <<= 1) {
      a0 += __shfl_xor(a0, off);
      a1 += __shfl_xor(a1, off);
      a2 += __shfl_xor(a2, off);
      a3 += __shfl_xor(a3, off);
    }
    if (sub == 0) {
      uint2 w; w.x = pack2(a0, a1); w.y = pack2(a2, a3);
      *(uint2*)&aggT[(((lg >> 1) * 16 + n) << 3) + ((lg & 1) << 2)] = w;
    }
  }
  __syncthreads();

  // ---- MFMA: this tile's 16 rows, wave wv computes output quadrant ct=wv ----
  short8 bf[NKC];
#pragma unroll
  for (int kc = 0; kc < NKC; ++kc) { U16 u; u.u = Bf[(kc * 4 + wv) * 64 + lane]; bf[kc] = u.s; }
  const float bc = bias[wv * 16 + (lane & 15)];
  const int r = lane & 15;
  const int gg = b * 16 + r;
  short8 a[NKC];
#pragma unroll
  for (int kc = 0; kc < NKC / 2; ++kc) {             // agg part from LDS
    const int chunk = kc * 4 + (lane >> 4);
    U16 u; u.u = *(const uint4*)&aggT[(chunk * 16 + r) << 3];
    a[kc] = u.s;
  }
#pragma unroll
  for (int kc = NKC / 2; kc < NKC; ++kc) {           // root part from global X
    const int colx = (kc - NKC / 2) * 32 + ((lane >> 4) << 3);
    U16 u; u.u = *(const uint4*)(X + (size_t)gg * DIN + colx);
    a[kc] = u.s;
  }
  f32x4 acc = {bc, bc, bc, bc};
#pragma unroll
  for (int kc = 0; kc < NKC; ++kc)
    acc = __builtin_amdgcn_mfma_f32_16x16x32_bf16(a[kc], bf[kc], acc, 0, 0, 0);
  const int col = wv * 16 + (lane & 15);
  if (!FUSE_POOL) {
    unsigned short* Y = (unsigned short*)outv;
#pragma unroll
    for (int j = 0; j < 4; ++j) {
      int grow = b * 16 + ((lane >> 4) << 2) + j;
      Y[(size_t)grow * 64 + col] = f2bf(fmaxf(acc[j], 0.f));
    }
  } else {
    float* sums = (float*)outv;
    const int g0 = batch[b * 16];
    const int g15 = batch[b * 16 + 15];
    if (g0 == g15) {
      // graph-uniform tile (~84%): full in-wave reduce, one line of atomics
      float v = fmaxf(acc[0], 0.f) + fmaxf(acc[1], 0.f)
              + fmaxf(acc[2], 0.f) + fmaxf(acc[3], 0.f);
      v += __shfl_xor(v, 16);
      v += __shfl_xor(v, 32);
      if ((lane >> 4) == 0)
        atomicAdd(&sums[(size_t)g0 * 64 + col], v);
    } else {
      // boundary tile: per-row atomics
#pragma unroll
      for (int j = 0; j < 4; ++j) {
        int grow = b * 16 + ((lane >> 4) << 2) + j;
        atomicAdd(&sums[(size_t)batch[grow] * 64 + col], fmaxf(acc[j], 0.f));
      }
    }
  }
}

// ------- classifier: one wave per graph; count via binary search on sorted batch -------
__global__ void __launch_bounds__(256)
k_cls(const float* __restrict__ sums, const int* __restrict__ batch,
      const float* __restrict__ cw, const float* __restrict__ cb,
      float* __restrict__ out) {
  const int g = blockIdx.x * 4 + (threadIdx.x >> 6);
  const int lane = threadIdx.x & 63;
  if (g >= N_GRAPHS) return;
  int lo = 0, hi = N_NODES;
  while (lo < hi) { int m = (lo + hi) >> 1; if (batch[m] < g) lo = m + 1; else hi = m; }
  int lo2 = lo, hi2 = N_NODES;
  while (lo2 < hi2) { int m = (lo2 + hi2) >> 1; if (batch[m] < g + 1) lo2 = m + 1; else hi2 = m; }
  int c_ = lo2 - lo;
  float p = sums[(size_t)g * 64 + lane] * (1.f / (float)(c_ > 0 ? c_ : 1));
  for (int c = 0; c < 10; ++c) {
    float v = p * cw[c * 64 + lane];
#pragma unroll
    for (int off = 1; off < 64; off <<= 1) v += __shfl_xor(v, off);
    if (lane == 0) out[g * 10 + c] = v + cb[c];
  }
}

extern "C" void kernel_launch(void* const* d_in, const int* in_sizes, int n_in,
                              void* d_out, int out_size, void* d_ws, size_t ws_size,
                              hipStream_t stream) {
  const int*   tok    = (const int*)d_in[0];
  const int*   eidx   = (const int*)d_in[1];
  const int*   batch  = (const int*)d_in[2];
  const float* semb   = (const float*)d_in[3];
  const float* cemb   = (const float*)d_in[4];
  const float* lw     = (const float*)d_in[5];
  const float* lb     = (const float*)d_in[6];
  const float* w1rel  = (const float*)d_in[7];
  const float* b1     = (const float*)d_in[8];
  const float* w1root = (const float*)d_in[9];
  const float* w2rel  = (const float*)d_in[10];
  const float* b2     = (const float*)d_in[11];
  const float* w2root = (const float*)d_in[12];
  const float* cw     = (const float*)d_in[13];
  const float* cb     = (const float*)d_in[14];
  const int* src = eidx;
  const int* dst = eidx + N_EDGES;

  char* p = (char*)d_ws;
  unsigned short* X1 = (unsigned short*)p;  p += (size_t)N_NODES * 32 * 2;   // 6.4 MB
  unsigned short* X2 = (unsigned short*)p;  p += (size_t)N_NODES * 64 * 2;   // 12.8 MB
  int*   tmp    = (int*)p;  p += (size_t)N_EDGES * 4;                        // 5 MB
  int*   esrc   = (int*)p;  p += (size_t)N_EDGES * 4;                        // 5 MB
  int*   degv   = (int*)p;  p += (size_t)N_NODES * 4;
  int*   rowst  = (int*)p;  p += (size_t)N_NODES * 4;
  int*   hist   = (int*)p;  p += (size_t)NBLK_F * NB * 4;                    // 1.56 MB
  int*   btotal = (int*)p;  p += 4096;
  float* sums   = (float*)p;  p += (size_t)N_GRAPHS * 64 * 4;                // 256 KB
  unsigned short* Bf1 = (unsigned short*)p;  p += 512 * 8 * 2;   // 8 KB
  unsigned short* Bf2 = (unsigned short*)p;  p += 1024 * 8 * 2;  // 16 KB

  hipMemsetAsync(sums, 0, (size_t)N_GRAPHS * 64 * 4, stream);

  // embed+lin | weight prep | coarse histograms — one launch, no global atomics
  k_front<<<EMB_BLKS + 6 + NBLK_F, 256, 0, stream>>>(
      tok, semb, cemb, lw, lb, X1,
      w1rel, w1root, w2rel, w2root, Bf1, Bf2, dst, hist);

  // deterministic counting-sort CSR; bbase computed in-block
  k_colscan<<<NB, 512, 0, stream>>>(hist, btotal);
  k_bfill<<<NBLK_F, 256, 0, stream>>>(src, dst, btotal, hist, tmp);
  k_bfinal<<<NB, 256, 0, stream>>>(btotal, tmp, degv, rowst, esrc);

  // per-tile conv layers; conv2 fuses mean-pool sums (no Y2 round-trip)
  k_conv<32, false><<<NB2, 256, 0, stream>>>(degv, rowst, esrc, X1, (const uint4*)Bf1,
                                             b1, nullptr, X2);
  k_conv<64, true><<<NB2, 256, 0, stream>>>(degv, rowst, esrc, X2, (const uint4*)Bf2,
                                            b2, batch, sums);

  // tiny classifier
  k_cls<<<N_GRAPHS / 4, 256, 0, stream>>>(sums, batch, cw, cb, (float*)d_out);
}

// Round 17
// 131.013 us; speedup vs baseline: 1.0688x; 1.0688x over previous
//
#include <hip/hip_runtime.h>

#define N_NODES  100000
#define N_EDGES  1250000
#define N_GRAPHS 1024
#define NB       ((N_NODES + 127) >> 7)     // 782 coarse buckets of 128 nodes
#define NB2      (N_NODES / 16)             // 6250 conv tiles of 16 nodes (exact)
#define NBLK_F   500                         // fill blocks
#define EPB      (N_EDGES / NBLK_F)          // 2500 edges per fill block (exact)
#define EMB_BLKS ((N_NODES + 255) / 256)     // 391
#define CAP      512                         // per-tile edge capacity (mean 200)

typedef __attribute__((ext_vector_type(8))) short short8;
typedef __attribute__((ext_vector_type(4))) float f32x4;
union U16 { uint4 u; short8 s; };

// ---- bf16 helpers (round-to-nearest-even) ----
__device__ __forceinline__ float bflo(unsigned int w) { return __uint_as_float(w << 16); }
__device__ __forceinline__ float bfhi(unsigned int w) { return __uint_as_float(w & 0xffff0000u); }
__device__ __forceinline__ unsigned short f2bf(float f) {
  unsigned int u = __float_as_uint(f);
  u = (u + 0x7fffu + ((u >> 16) & 1u)) >> 16;
  return (unsigned short)u;
}
__device__ __forceinline__ unsigned int pack2(float a, float b) {
  return (unsigned int)f2bf(a) | ((unsigned int)f2bf(b) << 16);
}

// ------- pack Wcat = [wrel; wroot] (2*DIN x 64) into MFMA B-fragments -------
template <int DIN>
__device__ __forceinline__ void prep_body(int t, const float* __restrict__ wrel,
                                          const float* __restrict__ wroot,
                                          unsigned short* __restrict__ Bf) {
  constexpr int NKC = (2 * DIN) / 32;
  if (t >= NKC * 4 * 64) return;
  int l = t & 63;
  int ct = (t >> 6) & 3;
  int kc = t >> 8;
  int col = ct * 16 + (l & 15);
#pragma unroll
  for (int e = 0; e < 8; ++e) {
    int k = kc * 32 + ((l >> 4) << 3) + e;
    float v = (k < DIN) ? wrel[col * DIN + k] : wroot[col * DIN + (k - DIN)];
    Bf[(size_t)t * 8 + e] = f2bf(v);
  }
}

// ------- fused front: embed+lin | weight prep | per-block coarse histogram -------
__global__ void __launch_bounds__(256)
k_front(const int* __restrict__ tok,
        const float* __restrict__ semb, const float* __restrict__ cemb,
        const float* __restrict__ lw, const float* __restrict__ lb,
        unsigned short* __restrict__ x1,          // [N,32] bf16
        const float* __restrict__ w1rel, const float* __restrict__ w1root,
        const float* __restrict__ w2rel, const float* __restrict__ w2root,
        unsigned short* __restrict__ Bf1, unsigned short* __restrict__ Bf2,
        const int* __restrict__ dst, int* __restrict__ hist) {
  __shared__ int lh[NB];
  const int t = threadIdx.x;
  const int bid = blockIdx.x;
  if (bid < EMB_BLKS) {
    int i = bid * 256 + t;
    if (i >= N_NODES) return;
    int s = tok[2 * i], c = tok[2 * i + 1];
    float e[16];
#pragma unroll
    for (int k = 0; k < 8; ++k) { e[k] = semb[s * 8 + k]; e[8 + k] = cemb[c * 8 + k]; }
    unsigned int w[16];
#pragma unroll
    for (int o = 0; o < 16; ++o) {
      float a0 = lb[2 * o], a1 = lb[2 * o + 1];
#pragma unroll
      for (int k = 0; k < 16; ++k) {
        a0 = fmaf(e[k], lw[(2 * o) * 16 + k], a0);
        a1 = fmaf(e[k], lw[(2 * o + 1) * 16 + k], a1);
      }
      w[o] = pack2(fmaxf(a0, 0.f), fmaxf(a1, 0.f));
    }
    uint4* d4 = (uint4*)(x1 + (size_t)i * 32);
#pragma unroll
    for (int q = 0; q < 4; ++q)
      d4[q] = make_uint4(w[4 * q], w[4 * q + 1], w[4 * q + 2], w[4 * q + 3]);
  } else if (bid < EMB_BLKS + 6) {
    int pb = bid - EMB_BLKS;
    if (pb < 2) prep_body<32>(pb * 256 + t, w1rel, w1root, Bf1);
    else prep_body<64>((pb - 2) * 256 + t, w2rel, w2root, Bf2);
  } else {
    const int blk = bid - EMB_BLKS - 6;           // 0..NBLK_F-1
    for (int i = t; i < NB; i += 256) lh[i] = 0;
    __syncthreads();
    const int start = blk * EPB;
    for (int e = start + t; e < start + EPB; e += 256)
      atomicAdd(&lh[dst[e] >> 7], 1);
    __syncthreads();
    int* hrow = hist + (size_t)blk * NB;          // [blk][bucket]: coalesced dump
    for (int i = t; i < NB; i += 256)
      hrow[i] = lh[i];
  }
}

// ------- per-bucket exclusive scan across fill blocks + bucket totals -------
__global__ void __launch_bounds__(512)
k_colscan(int* __restrict__ hist, int* __restrict__ btotal) {
  __shared__ int sc[512];
  const int b = blockIdx.x;
  const int t = threadIdx.x;
  int v = (t < NBLK_F) ? hist[(size_t)t * NB + b] : 0;
  sc[t] = v;
  __syncthreads();
  for (int off = 1; off < 512; off <<= 1) {
    int x = (t >= off) ? sc[t - off] : 0;
    __syncthreads();
    sc[t] += x;
    __syncthreads();
  }
  if (t < NBLK_F) hist[(size_t)t * NB + b] = sc[t] - v;
  if (t == 511) btotal[b] = sc[511];
}

// ------- fill: cursors = in-block scan(btotal) + per-block offset -------
__global__ void __launch_bounds__(256)
k_bfill(const int* __restrict__ src, const int* __restrict__ dst,
        const int* __restrict__ btotal, const int* __restrict__ hist,
        int* __restrict__ tmp) {
  __shared__ int cur[NB];
  __shared__ int spart[256];
  const int t = threadIdx.x;
  const int blk = blockIdx.x;
  const int* hrow = hist + (size_t)blk * NB;
  int v[4]; int s = 0;
#pragma unroll
  for (int j = 0; j < 4; ++j) {
    int idx = t * 4 + j;
    v[j] = (idx < NB) ? btotal[idx] : 0;
    s += v[j];
  }
  spart[t] = s;
  __syncthreads();
  for (int off = 1; off < 256; off <<= 1) {
    int x = (t >= off) ? spart[t - off] : 0;
    __syncthreads();
    spart[t] += x;
    __syncthreads();
  }
  int run = spart[t] - s;
#pragma unroll
  for (int j = 0; j < 4; ++j) {
    int idx = t * 4 + j;
    if (idx < NB) cur[idx] = run + hrow[idx];
    run += v[j];
  }
  __syncthreads();
  const int start = blk * EPB;
  for (int e = start + t; e < start + EPB; e += 256) {
    int d = dst[e];
    int pos = atomicAdd(&cur[d >> 7], 1);         // LDS only; block-owned range
    tmp[pos] = (src[e] << 7) | (d & 127);
  }
}

// ------- per-128-bucket finalize: full node sort -> esrc, deg, rowst -------
__global__ void __launch_bounds__(256)
k_bfinal(const int* __restrict__ btotal, const int* __restrict__ tmp,
         int* __restrict__ deg, int* __restrict__ rowst,
         int* __restrict__ esrc) {
  __shared__ int spart[256];
  __shared__ int h[128], sc[128], cur[128];
  __shared__ int s_base;
  const int t = threadIdx.x;
  const int b = blockIdx.x;
  int s = 0;
  for (int i = t; i < b; i += 256) s += btotal[i];
  spart[t] = s;
  if (t < 128) h[t] = 0;
  __syncthreads();
  for (int off = 128; off >= 1; off >>= 1) {
    if (t < off) spart[t] += spart[t + off];
    __syncthreads();
  }
  if (t == 0) s_base = spart[0];
  __syncthreads();
  const int base = s_base, cnt = btotal[b];
  for (int i = t; i < cnt; i += 256) atomicAdd(&h[tmp[base + i] & 127], 1);
  __syncthreads();
  if (t < 128) sc[t] = h[t];
  __syncthreads();
  for (int off = 1; off < 128; off <<= 1) {
    int v = 0;
    if (t < 128 && t >= off) v = sc[t - off];
    __syncthreads();
    if (t < 128) sc[t] += v;
    __syncthreads();
  }
  if (t < 128) {
    int excl = sc[t] - h[t];
    cur[t] = excl;
    int node = (b << 7) + t;
    if (node < N_NODES) { deg[node] = h[t]; rowst[node] = base + excl; }
  }
  __syncthreads();
  for (int i = t; i < cnt; i += 256) {
    int v = tmp[base + i];
    int p = atomicAdd(&cur[v & 127], 1);
    esrc[base + p] = v >> 7;
  }
}

// ======= per-tile conv (r15 structure): stage sorted segment, uint2 reg-gather, MFMA =======
// UNR independent row-loads in flight per lane (UNR*GROUPS edges per iteration).
template <int DIN, int UNR>
__global__ void __launch_bounds__(256)
k_conv(const int* __restrict__ deg, const int* __restrict__ rowst,
       const int* __restrict__ esrc,
       const unsigned short* __restrict__ X,    // [N,DIN] bf16
       const uint4* __restrict__ Bf,            // MFMA B-fragments, K=2*DIN
       const float* __restrict__ bias,          // [64]
       unsigned short* __restrict__ Y) {        // [N,64] bf16
  constexpr int NKC = (2 * DIN) / 32;      // 2 (conv1) / 4 (conv2)
  constexpr int LPGu = DIN / 4;            // lanes per edge (uint2 slice): 8 / 16
  constexpr int GROUPS = 64 / LPGu;        // 8 / 4
  __shared__ int lsrc[CAP];
  __shared__ int hdeg[16], hbase[16];
  __shared__ int s_cnt, s_base;
  __shared__ unsigned short aggT[(DIN / 8) * 16 * 8];   // [chunk][row][8] bf16
  const int t = threadIdx.x;
  const int lane = t & 63;
  const int wv = t >> 6;
  const int b = blockIdx.x;                // 16-node tile
  if (t < 16) hdeg[t] = deg[b * 16 + t];
  __syncthreads();
  if (t == 0) {
    int run = 0;
#pragma unroll
    for (int n = 0; n < 16; ++n) { hbase[n] = run; run += hdeg[n]; }
    s_cnt = min(run, CAP);
    s_base = rowst[b * 16];
  }
  __syncthreads();
  const int cnt = s_cnt, base = s_base;
  for (int i = t; i < cnt; i += 256) lsrc[i] = esrc[base + i];   // pre-sorted
  __syncthreads();

  // ---- gather: wave wv accumulates its 4 nodes in registers ----
  const int sub = lane / LPGu;
  const int lg = lane % LPGu;
#pragma unroll
  for (int k = 0; k < 4; ++k) {
    const int n = wv * 4 + k;
    const int dgn = hdeg[n];
    const int eb = hbase[n];
    float a0 = 0.f, a1 = 0.f, a2 = 0.f, a3 = 0.f;
    for (int j = 0; j < dgn; j += UNR * GROUPS) {
      int e[UNR]; uint2 r[UNR];
#pragma unroll
      for (int u = 0; u < UNR; ++u) {
        e[u] = j + u * GROUPS + sub;
        int s0 = lsrc[min(eb + min(e[u], dgn - 1), CAP - 1)];
        r[u] = *((const uint2*)(X + (size_t)s0 * DIN) + lg);
      }
#pragma unroll
      for (int u = 0; u < UNR; ++u) {
        if (e[u] < dgn) {
          a0 += bflo(r[u].x); a1 += bfhi(r[u].x);
          a2 += bflo(r[u].y); a3 += bfhi(r[u].y);
        }
      }
    }
#pragma unroll
    for (int off = LPGu; off < 64; off <<= 1) {
      a0 += __shfl_xor(a0, off);
      a1 += __shfl_xor(a1, off);
      a2 += __shfl_xor(a2, off);
      a3 += __shfl_xor(a3, off);
    }
    if (sub == 0) {
      uint2 w; w.x = pack2(a0, a1); w.y = pack2(a2, a3);
      *(uint2*)&aggT[(((lg >> 1) * 16 + n) << 3) + ((lg & 1) << 2)] = w;
    }
  }
  __syncthreads();

  // ---- MFMA: this tile's 16 rows, wave wv computes output quadrant ct=wv ----
  short8 bf[NKC];
#pragma unroll
  for (int kc = 0; kc < NKC; ++kc) { U16 u; u.u = Bf[(kc * 4 + wv) * 64 + lane]; bf[kc] = u.s; }
  const float bc = bias[wv * 16 + (lane & 15)];
  const int r = lane & 15;
  const int gg = b * 16 + r;
  short8 a[NKC];
#pragma unroll
  for (int kc = 0; kc < NKC / 2; ++kc) {             // agg part from LDS
    const int chunk = kc * 4 + (lane >> 4);
    U16 u; u.u = *(const uint4*)&aggT[(chunk * 16 + r) << 3];
    a[kc] = u.s;
  }
#pragma unroll
  for (int kc = NKC / 2; kc < NKC; ++kc) {           // root part from global X
    const int colx = (kc - NKC / 2) * 32 + ((lane >> 4) << 3);
    U16 u; u.u = *(const uint4*)(X + (size_t)gg * DIN + colx);
    a[kc] = u.s;
  }
  f32x4 acc = {bc, bc, bc, bc};
#pragma unroll
  for (int kc = 0; kc < NKC; ++kc)
    acc = __builtin_amdgcn_mfma_f32_16x16x32_bf16(a[kc], bf[kc], acc, 0, 0, 0);
  const int col = wv * 16 + (lane & 15);
#pragma unroll
  for (int j = 0; j < 4; ++j) {
    int grow = b * 16 + ((lane >> 4) << 2) + j;
    Y[(size_t)grow * 64 + col] = f2bf(fmaxf(acc[j], 0.f));
  }
}

// ------- fused mean-pool + classifier: one block per graph, batch is sorted -------
__global__ void __launch_bounds__(256)
k_pool(const unsigned short* __restrict__ y2,   // [N,64] bf16
       const int* __restrict__ batch,
       const float* __restrict__ cw, const float* __restrict__ cb,
       float* __restrict__ out) {
  __shared__ float part[4][64];
  const int g = blockIdx.x;
  const int lane = threadIdx.x & 63;
  const int wv = threadIdx.x >> 6;
  int lo = 0, hi = N_NODES;
  while (lo < hi) { int m = (lo + hi) >> 1; if (batch[m] < g) lo = m + 1; else hi = m; }
  int lo2 = lo, hi2 = N_NODES;
  while (lo2 < hi2) { int m = (lo2 + hi2) >> 1; if (batch[m] < g + 1) lo2 = m + 1; else hi2 = m; }
  float s = 0.f;
  for (int r = lo + wv; r < lo2; r += 4)
    s += __uint_as_float((unsigned int)y2[(size_t)r * 64 + lane] << 16);
  part[wv][lane] = s;
  __syncthreads();
  if (wv == 0) {
    float p = part[0][lane] + part[1][lane] + part[2][lane] + part[3][lane];
    int c_ = lo2 - lo;
    p *= 1.f / (float)(c_ > 0 ? c_ : 1);
    for (int c = 0; c < 10; ++c) {
      float v = p * cw[c * 64 + lane];
#pragma unroll
      for (int off = 1; off < 64; off <<= 1) v += __shfl_xor(v, off);
      if (lane == 0) out[g * 10 + c] = v + cb[c];
    }
  }
}

extern "C" void kernel_launch(void* const* d_in, const int* in_sizes, int n_in,
                              void* d_out, int out_size, void* d_ws, size_t ws_size,
                              hipStream_t stream) {
  const int*   tok    = (const int*)d_in[0];
  const int*   eidx   = (const int*)d_in[1];
  const int*   batch  = (const int*)d_in[2];
  const float* semb   = (const float*)d_in[3];
  const float* cemb   = (const float*)d_in[4];
  const float* lw     = (const float*)d_in[5];
  const float* lb     = (const float*)d_in[6];
  const float* w1rel  = (const float*)d_in[7];
  const float* b1     = (const float*)d_in[8];
  const float* w1root = (const float*)d_in[9];
  const float* w2rel  = (const float*)d_in[10];
  const float* b2     = (const float*)d_in[11];
  const float* w2root = (const float*)d_in[12];
  const float* cw     = (const float*)d_in[13];
  const float* cb     = (const float*)d_in[14];
  const int* src = eidx;
  const int* dst = eidx + N_EDGES;

  char* p = (char*)d_ws;
  unsigned short* X1 = (unsigned short*)p;  p += (size_t)N_NODES * 32 * 2;   // 6.4 MB
  unsigned short* X2 = (unsigned short*)p;  p += (size_t)N_NODES * 64 * 2;   // 12.8 MB
  unsigned short* Y2 = (unsigned short*)p;  p += (size_t)N_NODES * 64 * 2;   // 12.8 MB
  int*   tmp    = (int*)p;  p += (size_t)N_EDGES * 4;                        // 5 MB
  int*   esrc   = (int*)p;  p += (size_t)N_EDGES * 4;                        // 5 MB
  int*   degv   = (int*)p;  p += (size_t)N_NODES * 4;
  int*   rowst  = (int*)p;  p += (size_t)N_NODES * 4;
  int*   hist   = (int*)p;  p += (size_t)NBLK_F * NB * 4;                    // 1.56 MB
  int*   btotal = (int*)p;  p += 4096;
  unsigned short* Bf1 = (unsigned short*)p;  p += 512 * 8 * 2;   // 8 KB
  unsigned short* Bf2 = (unsigned short*)p;  p += 1024 * 8 * 2;  // 16 KB

  // embed+lin | weight prep | coarse histograms — one launch, no global atomics
  k_front<<<EMB_BLKS + 6 + NBLK_F, 256, 0, stream>>>(
      tok, semb, cemb, lw, lb, X1,
      w1rel, w1root, w2rel, w2root, Bf1, Bf2, dst, hist);

  // deterministic counting-sort CSR; bbase computed in-block (no k_bscan launch)
  k_colscan<<<NB, 512, 0, stream>>>(hist, btotal);
  k_bfill<<<NBLK_F, 256, 0, stream>>>(src, dst, btotal, hist, tmp);
  k_bfinal<<<NB, 256, 0, stream>>>(btotal, tmp, degv, rowst, esrc);

  // per-tile conv layers; conv2 gather runs 4 loads in flight (latency-bound fix)
  k_conv<32, 2><<<NB2, 256, 0, stream>>>(degv, rowst, esrc, X1, (const uint4*)Bf1, b1, X2);
  k_conv<64, 4><<<NB2, 256, 0, stream>>>(degv, rowst, esrc, X2, (const uint4*)Bf2, b2, Y2);

  // fused mean-pool + classifier
  k_pool<<<N_GRAPHS, 256, 0, stream>>>(Y2, batch, cw, cb, (float*)d_out);
}